// Round 6
// baseline (40095.126 us; speedup 1.0000x reference)
//
#include <hip/hip_runtime.h>
#include <stdint.h>

#define T_LEN 4096
#define E_DIM 256
#define HH 256

typedef unsigned long long u64;

__device__ __forceinline__ float sigmoidf_(float x) {
    return __builtin_amdgcn_rcpf(1.0f + __expf(-x));
}
__device__ __forceinline__ float tanh_fast(float x) {
    float e = __expf(2.0f * x);
    return 1.0f - 2.0f * __builtin_amdgcn_rcpf(e + 1.0f);
}

// ---------------------------------------------------------------------------
// Kernel 1: embedding gather fused with input projection (unchanged).
// ---------------------------------------------------------------------------
__global__ __launch_bounds__(256) void proj_kernel(
    const int* __restrict__ sent, const float* __restrict__ embed,
    const float* __restrict__ Wih_f, const float* __restrict__ bih_f, const float* __restrict__ bhh_f,
    const float* __restrict__ Wih_b, const float* __restrict__ bih_b, const float* __restrict__ bhh_b,
    float* __restrict__ gates_f, float* __restrict__ gates_b)
{
    __shared__ float4 xt[16][64];
    const int tid = threadIdx.x;
    const int dir = blockIdx.y;
    const int t0  = blockIdx.x * 16;

    const float* Wih = dir ? Wih_b : Wih_f;
    const float* bih = dir ? bih_b : bih_f;
    const float* bhh = dir ? bhh_b : bhh_f;
    float* gates     = dir ? gates_b : gates_f;

    {
        int row = tid >> 4;
        int c   = tid & 15;
        const float4* src = (const float4*)(embed + (size_t)sent[t0 + row] * E_DIM);
        xt[row][c]      = src[c];
        xt[row][c + 16] = src[c + 16];
        xt[row][c + 32] = src[c + 32];
        xt[row][c + 48] = src[c + 48];
    }
    __syncthreads();

    float acc[4][16];
    #pragma unroll
    for (int ri = 0; ri < 4; ++ri)
        #pragma unroll
        for (int tt = 0; tt < 16; ++tt) acc[ri][tt] = 0.f;

    const float4* wrow0 = (const float4*)(Wih + (size_t)(0 * 256 + tid) * 256);
    const float4* wrow1 = (const float4*)(Wih + (size_t)(1 * 256 + tid) * 256);
    const float4* wrow2 = (const float4*)(Wih + (size_t)(2 * 256 + tid) * 256);
    const float4* wrow3 = (const float4*)(Wih + (size_t)(3 * 256 + tid) * 256);

    for (int k4 = 0; k4 < 64; ++k4) {
        float4 xv[16];
        #pragma unroll
        for (int tt = 0; tt < 16; ++tt) xv[tt] = xt[tt][k4];
        float4 w0 = wrow0[k4], w1 = wrow1[k4], w2 = wrow2[k4], w3 = wrow3[k4];
        #pragma unroll
        for (int tt = 0; tt < 16; ++tt) {
            acc[0][tt] += w0.x*xv[tt].x + w0.y*xv[tt].y + w0.z*xv[tt].z + w0.w*xv[tt].w;
            acc[1][tt] += w1.x*xv[tt].x + w1.y*xv[tt].y + w1.z*xv[tt].z + w1.w*xv[tt].w;
            acc[2][tt] += w2.x*xv[tt].x + w2.y*xv[tt].y + w2.z*xv[tt].z + w2.w*xv[tt].w;
            acc[3][tt] += w3.x*xv[tt].x + w3.y*xv[tt].y + w3.z*xv[tt].z + w3.w*xv[tt].w;
        }
    }

    #pragma unroll
    for (int ri = 0; ri < 4; ++ri) {
        int r = ri * 256 + tid;
        float b = bih[r] + bhh[r];
        #pragma unroll
        for (int tt = 0; tt < 16; ++tt)
            gates[(size_t)(t0 + tt) * 1024 + r] = acc[ri][tt] + b;
    }
}

// ---------------------------------------------------------------------------
// Kernel 2: BiLSTM recurrence, DUAL-DIRECTION INTERLEAVED.
// 8 blocks; block b owns hidden j = b*32..b*32+31 for BOTH directions
// (128+128 gate rows x 256 k = 256KB register-resident, asm-pinned).
// Thread (jl = tid>>4, s = tid&15): 4 gates x k-slice s*16..s*16+15, both
// dirs. Per step: poll f -> dot f -> publish f -> poll b -> dot b -> publish
// b. The ~L3-latency handoff of one direction overlaps the compute of the
// other. NO barriers, NO LDS: each thread polls exactly the 16 msg slots its
// dot consumes (8B-atomic u64 loads -> no tag/value tearing), straight into
// registers. ABA-safe: tag t+2 stored only after poll saw all tags t+1,
// which implies every reader consumed tag t from the slots being overwritten.
// ---------------------------------------------------------------------------
__global__ __launch_bounds__(512, 1) void lstm_kernel(
    const float* __restrict__ Whh_f, const float* __restrict__ Whh_b,
    const float* __restrict__ gates_f, const float* __restrict__ gates_b,
    const float* __restrict__ h0, const float* __restrict__ c0,
    float* __restrict__ h_out, u64* __restrict__ msg)
{
    const int b   = blockIdx.x;       // 0..7
    const int tid = threadIdx.x;
    const int s   = tid & 15;         // k-slice 0..15 (16 k each)
    const int jl  = tid >> 4;         // 0..31
    const int j   = b * 32 + jl;      // hidden index 0..255

    // register-resident weights: wf/wb[g*16+c] = Whh_d[(g*256+j)*256 + s*16+c]
    float wf[64], wb[64];
    #pragma unroll
    for (int g = 0; g < 4; ++g) {
        const float4* rf = (const float4*)(Whh_f + (size_t)(g * 256 + j) * 256 + s * 16);
        const float4* rb = (const float4*)(Whh_b + (size_t)(g * 256 + j) * 256 + s * 16);
        #pragma unroll
        for (int i = 0; i < 4; ++i) {
            float4 vf = rf[i], vb = rb[i];
            wf[g*16 + i*4 + 0] = vf.x; wf[g*16 + i*4 + 1] = vf.y;
            wf[g*16 + i*4 + 2] = vf.z; wf[g*16 + i*4 + 3] = vf.w;
            wb[g*16 + i*4 + 0] = vb.x; wb[g*16 + i*4 + 1] = vb.y;
            wb[g*16 + i*4 + 2] = vb.z; wb[g*16 + i*4 + 3] = vb.w;
        }
    }
    #pragma unroll
    for (int k = 0; k < 64; ++k) {
        asm volatile("" : "+v"(wf[k]));
        asm volatile("" : "+v"(wb[k]));
    }

    // init: tag 1 (h0) into parity-0 slots, both directions (redundant x8
    // blocks, identical values -> benign)
    if (tid < 256) {
        u64 pf = ((u64)1u << 32) | (u64)__float_as_uint(h0[tid]);
        u64 pb = ((u64)1u << 32) | (u64)__float_as_uint(h0[HH + tid]);
        __hip_atomic_store(&msg[(0 * 2 + 0) * 256 + tid], pf,
                           __ATOMIC_RELAXED, __HIP_MEMORY_SCOPE_AGENT);
        __hip_atomic_store(&msg[(0 * 2 + 1) * 256 + tid], pb,
                           __ATOMIC_RELAXED, __HIP_MEMORY_SCOPE_AGENT);
    }
    float cf = 0.f, cb = 0.f;
    if (s == 0) { cf = c0[j]; cb = c0[HH + j]; }

    for (int t = 0; t < T_LEN; ++t) {
        const int tb = T_LEN - 1 - t;
        const unsigned want = (unsigned)(t + 1);
        const u64 newtag = ((u64)(unsigned)(t + 2)) << 32;

        // finalists prefetch both directions' gate inputs up front
        float gf0 = 0.f, gf1 = 0.f, gf2 = 0.f, gf3 = 0.f;
        float gb0 = 0.f, gb1 = 0.f, gb2 = 0.f, gb3 = 0.f;
        if (s == 0) {
            const float* gpf = gates_f + (size_t)t  * 1024 + j;
            const float* gpb = gates_b + (size_t)tb * 1024 + j;
            gf0 = gpf[0]; gf1 = gpf[256]; gf2 = gpf[512]; gf3 = gpf[768];
            gb0 = gpb[0]; gb1 = gpb[256]; gb2 = gpb[512]; gb3 = gpb[768];
        }

        // ================= forward direction =================
        float hv[16];
        {
            u64* p = &msg[((t & 1) * 2 + 0) * 256 + s * 16];
            u64 m[16];
            for (;;) {
                #pragma unroll
                for (int i = 0; i < 16; ++i)
                    m[i] = __hip_atomic_load(&p[i], __ATOMIC_RELAXED,
                                             __HIP_MEMORY_SCOPE_AGENT);
                unsigned bad = 0;
                #pragma unroll
                for (int i = 0; i < 16; ++i) bad |= (unsigned)(m[i] >> 32) ^ want;
                if (bad == 0) break;
            }
            #pragma unroll
            for (int i = 0; i < 16; ++i) hv[i] = __uint_as_float((unsigned)m[i]);
        }
        {
            float p0 = 0.f, p1 = 0.f, p2 = 0.f, p3 = 0.f;
            #pragma unroll
            for (int c = 0; c < 16; ++c) {
                float h = hv[c];
                p0 += wf[c] * h; p1 += wf[16 + c] * h;
                p2 += wf[32 + c] * h; p3 += wf[48 + c] * h;
            }
            #pragma unroll
            for (int mk = 1; mk <= 8; mk <<= 1) {
                p0 += __shfl_xor(p0, mk); p1 += __shfl_xor(p1, mk);
                p2 += __shfl_xor(p2, mk); p3 += __shfl_xor(p3, mk);
            }
            if (s == 0) {
                float iv = sigmoidf_(gf0 + p0);
                float fv = sigmoidf_(gf1 + p1);
                float gv = tanh_fast(gf2 + p2);
                float ov = sigmoidf_(gf3 + p3);
                cf = fv * cf + iv * gv;
                float h = ov * tanh_fast(cf);
                __hip_atomic_store(&msg[(((t + 1) & 1) * 2 + 0) * 256 + j],
                                   newtag | (u64)__float_as_uint(h),
                                   __ATOMIC_RELAXED, __HIP_MEMORY_SCOPE_AGENT);
                h_out[(size_t)t * 512 + j] = h;
            }
        }

        // ================= backward direction =================
        {
            u64* p = &msg[((t & 1) * 2 + 1) * 256 + s * 16];
            u64 m[16];
            for (;;) {
                #pragma unroll
                for (int i = 0; i < 16; ++i)
                    m[i] = __hip_atomic_load(&p[i], __ATOMIC_RELAXED,
                                             __HIP_MEMORY_SCOPE_AGENT);
                unsigned bad = 0;
                #pragma unroll
                for (int i = 0; i < 16; ++i) bad |= (unsigned)(m[i] >> 32) ^ want;
                if (bad == 0) break;
            }
            #pragma unroll
            for (int i = 0; i < 16; ++i) hv[i] = __uint_as_float((unsigned)m[i]);
        }
        {
            float p0 = 0.f, p1 = 0.f, p2 = 0.f, p3 = 0.f;
            #pragma unroll
            for (int c = 0; c < 16; ++c) {
                float h = hv[c];
                p0 += wb[c] * h; p1 += wb[16 + c] * h;
                p2 += wb[32 + c] * h; p3 += wb[48 + c] * h;
            }
            #pragma unroll
            for (int mk = 1; mk <= 8; mk <<= 1) {
                p0 += __shfl_xor(p0, mk); p1 += __shfl_xor(p1, mk);
                p2 += __shfl_xor(p2, mk); p3 += __shfl_xor(p3, mk);
            }
            if (s == 0) {
                float iv = sigmoidf_(gb0 + p0);
                float fv = sigmoidf_(gb1 + p1);
                float gv = tanh_fast(gb2 + p2);
                float ov = sigmoidf_(gb3 + p3);
                cb = fv * cb + iv * gv;
                float h = ov * tanh_fast(cb);
                __hip_atomic_store(&msg[(((t + 1) & 1) * 2 + 1) * 256 + j],
                                   newtag | (u64)__float_as_uint(h),
                                   __ATOMIC_RELAXED, __HIP_MEMORY_SCOPE_AGENT);
                h_out[(size_t)tb * 512 + HH + j] = h;
            }
        }
    }
}

// ---------------------------------------------------------------------------
// Kernel 3: feats[t][k] = dot(h_out[t,:], W_out[k,:]) + b_out[k]
// ---------------------------------------------------------------------------
__global__ __launch_bounds__(64) void feats_kernel(
    const float* __restrict__ h_out, const float* __restrict__ W_out,
    const float* __restrict__ b_out, float* __restrict__ feats)
{
    const int t = blockIdx.x;
    const int lane = threadIdx.x;
    const int k = lane >> 1, half = lane & 1;
    const float4* hv = (const float4*)(h_out + (size_t)t * 512 + half * 256);
    const float4* wv = (const float4*)(W_out + (size_t)k * 512 + half * 256);
    float p = 0.f;
    #pragma unroll 16
    for (int i = 0; i < 64; ++i) {
        float4 a = hv[i], b = wv[i];
        p += a.x*b.x + a.y*b.y + a.z*b.z + a.w*b.w;
    }
    p += __shfl_xor(p, 1);
    if (half == 0) feats[t * 32 + k] = p + b_out[k];
}

// ---------------------------------------------------------------------------
// Kernel 4: Viterbi. Single wave; feats chunked through LDS; alpha broadcast
// via LDS float4 reads (replaces 16 shfl/iter). Backpointers in LDS.
// ---------------------------------------------------------------------------
#define VT_CHUNK 128
__global__ __launch_bounds__(64) void viterbi_kernel(
    const float* __restrict__ feats, const float* __restrict__ trans,
    float* __restrict__ out)
{
    extern __shared__ unsigned char dynls[];
    unsigned char* ixs = dynls;                       // (T-1)*32 = 131040 B
    float* fchunk = (float*)(dynls + 131072);         // VT_CHUNK*32 floats
    __shared__ float abuf[32];
    __shared__ float fin[32];

    const int lane = threadIdx.x;
    const int j = lane >> 1, ih = lane & 1;

    float ttr[16];
    #pragma unroll
    for (int q = 0; q < 16; ++q) ttr[q] = trans[(ih * 16 + q) * 32 + j];

    float alpha = 0.f;

    for (int cs = 0; cs < T_LEN; cs += VT_CHUNK) {
        const float4* src = (const float4*)(feats + (size_t)cs * 32);
        float4* dst = (float4*)fchunk;
        #pragma unroll
        for (int i = 0; i < 16; ++i) dst[lane + 64 * i] = src[lane + 64 * i];
        __syncthreads();

        int tbeg = cs;
        if (cs == 0) { alpha = fchunk[j]; tbeg = 1; }

        for (int t = tbeg; t < cs + VT_CHUNK; ++t) {
            float obs = fchunk[(t - cs) * 32 + j];
            // single wave: in-order LDS, no barrier needed
            if (ih == 0) abuf[j] = alpha;
            float av[16];
            {
                const float4* ap = (const float4*)&abuf[ih * 16];
                #pragma unroll
                for (int q4 = 0; q4 < 4; ++q4) {
                    float4 a = ap[q4];
                    av[q4*4+0] = a.x; av[q4*4+1] = a.y;
                    av[q4*4+2] = a.z; av[q4*4+3] = a.w;
                }
            }
            float v[16]; int ix[16];
            #pragma unroll
            for (int q = 0; q < 16; ++q) {
                v[q] = (av[q] + ttr[q]) + obs;
                ix[q] = ih * 16 + q;
            }
            #pragma unroll
            for (int st = 8; st >= 1; st >>= 1)
                #pragma unroll
                for (int q = 0; q < 8; ++q)
                    if (q < st && v[q + st] > v[q]) { v[q] = v[q + st]; ix[q] = ix[q + st]; }
            float best = v[0]; int barg = ix[0];

            // merge the two i-halves; lower i wins exact ties
            float ob = __shfl_xor(best, 1); int oa = __shfl_xor(barg, 1);
            float m0 = ih ? ob : best; int a0 = ih ? oa : barg;
            float m1 = ih ? best : ob; int a1 = ih ? barg : oa;
            float m = m0; int a = a0;
            if (m1 > m0) { m = m1; a = a1; }
            if (ih == 0) ixs[(t - 1) * 32 + j] = (unsigned char)a;
            alpha = m;
        }
        __syncthreads();
    }

    if (ih == 0) fin[j] = alpha;
    __syncthreads();

    if (lane == 0) {
        float sc = fin[0]; int cur = 0;
        for (int q = 1; q < 32; ++q)
            if (fin[q] > sc) { sc = fin[q]; cur = q; }
        out[T_LEN] = sc;
        out[T_LEN - 1] = (float)cur;
        for (int t = T_LEN - 2; t >= 0; --t) {
            cur = ixs[t * 32 + cur];
            out[t] = (float)cur;
        }
    }
}

// ---------------------------------------------------------------------------
extern "C" void kernel_launch(void* const* d_in, const int* in_sizes, int n_in,
                              void* d_out, int out_size, void* d_ws, size_t ws_size,
                              hipStream_t stream) {
    const int*   sent  = (const int*)d_in[0];
    const float* embed = (const float*)d_in[1];
    const float* Wih_f = (const float*)d_in[2];
    const float* Whh_f = (const float*)d_in[3];
    const float* bih_f = (const float*)d_in[4];
    const float* bhh_f = (const float*)d_in[5];
    const float* Wih_b = (const float*)d_in[6];
    const float* Whh_b = (const float*)d_in[7];
    const float* bih_b = (const float*)d_in[8];
    const float* bhh_b = (const float*)d_in[9];
    const float* h0    = (const float*)d_in[10];
    const float* c0    = (const float*)d_in[11];
    const float* W_out = (const float*)d_in[12];
    const float* b_out = (const float*)d_in[13];
    const float* trans = (const float*)d_in[14];
    float* out = (float*)d_out;

    float* gates_f = (float*)d_ws;                              // T*1024
    float* gates_b = gates_f + (size_t)T_LEN * 1024;            // T*1024
    float* h_out   = gates_b + (size_t)T_LEN * 1024;            // T*512
    float* feats   = h_out   + (size_t)T_LEN * 512;             // T*32
    u64*   msg     = (u64*)(feats + (size_t)T_LEN * 32);        // 2*2*256

    dim3 gproj(T_LEN / 16, 2);
    proj_kernel<<<gproj, 256, 0, stream>>>(sent, embed,
        Wih_f, bih_f, bhh_f, Wih_b, bih_b, bhh_b, gates_f, gates_b);

    lstm_kernel<<<8, 512, 0, stream>>>(Whh_f, Whh_b, gates_f, gates_b,
                                       h0, c0, h_out, msg);

    feats_kernel<<<T_LEN, 64, 0, stream>>>(h_out, W_out, b_out, feats);

    hipFuncSetAttribute((const void*)viterbi_kernel,
                        hipFuncAttributeMaxDynamicSharedMemorySize, 147456);
    viterbi_kernel<<<1, 64, 147456, stream>>>(feats, trans, out);
}

// Round 7
// 16664.259 us; speedup vs baseline: 2.4061x; 2.4061x over previous
//
#include <hip/hip_runtime.h>
#include <stdint.h>

#define T_LEN 4096
#define E_DIM 256
#define HH 256

typedef unsigned long long u64;

__device__ __forceinline__ float sigmoidf_(float x) {
    return __builtin_amdgcn_rcpf(1.0f + __expf(-x));
}
__device__ __forceinline__ float tanh_fast(float x) {
    float e = __expf(2.0f * x);
    return 1.0f - 2.0f * __builtin_amdgcn_rcpf(e + 1.0f);
}

// ---------------------------------------------------------------------------
// Kernel 1: embedding gather fused with input projection (unchanged).
// ---------------------------------------------------------------------------
__global__ __launch_bounds__(256) void proj_kernel(
    const int* __restrict__ sent, const float* __restrict__ embed,
    const float* __restrict__ Wih_f, const float* __restrict__ bih_f, const float* __restrict__ bhh_f,
    const float* __restrict__ Wih_b, const float* __restrict__ bih_b, const float* __restrict__ bhh_b,
    float* __restrict__ gates_f, float* __restrict__ gates_b)
{
    __shared__ float4 xt[16][64];
    const int tid = threadIdx.x;
    const int dir = blockIdx.y;
    const int t0  = blockIdx.x * 16;

    const float* Wih = dir ? Wih_b : Wih_f;
    const float* bih = dir ? bih_b : bih_f;
    const float* bhh = dir ? bhh_b : bhh_f;
    float* gates     = dir ? gates_b : gates_f;

    {
        int row = tid >> 4;
        int c   = tid & 15;
        const float4* src = (const float4*)(embed + (size_t)sent[t0 + row] * E_DIM);
        xt[row][c]      = src[c];
        xt[row][c + 16] = src[c + 16];
        xt[row][c + 32] = src[c + 32];
        xt[row][c + 48] = src[c + 48];
    }
    __syncthreads();

    float acc[4][16];
    #pragma unroll
    for (int ri = 0; ri < 4; ++ri)
        #pragma unroll
        for (int tt = 0; tt < 16; ++tt) acc[ri][tt] = 0.f;

    const float4* wrow0 = (const float4*)(Wih + (size_t)(0 * 256 + tid) * 256);
    const float4* wrow1 = (const float4*)(Wih + (size_t)(1 * 256 + tid) * 256);
    const float4* wrow2 = (const float4*)(Wih + (size_t)(2 * 256 + tid) * 256);
    const float4* wrow3 = (const float4*)(Wih + (size_t)(3 * 256 + tid) * 256);

    for (int k4 = 0; k4 < 64; ++k4) {
        float4 xv[16];
        #pragma unroll
        for (int tt = 0; tt < 16; ++tt) xv[tt] = xt[tt][k4];
        float4 w0 = wrow0[k4], w1 = wrow1[k4], w2 = wrow2[k4], w3 = wrow3[k4];
        #pragma unroll
        for (int tt = 0; tt < 16; ++tt) {
            acc[0][tt] += w0.x*xv[tt].x + w0.y*xv[tt].y + w0.z*xv[tt].z + w0.w*xv[tt].w;
            acc[1][tt] += w1.x*xv[tt].x + w1.y*xv[tt].y + w1.z*xv[tt].z + w1.w*xv[tt].w;
            acc[2][tt] += w2.x*xv[tt].x + w2.y*xv[tt].y + w2.z*xv[tt].z + w2.w*xv[tt].w;
            acc[3][tt] += w3.x*xv[tt].x + w3.y*xv[tt].y + w3.z*xv[tt].z + w3.w*xv[tt].w;
        }
    }

    #pragma unroll
    for (int ri = 0; ri < 4; ++ri) {
        int r = ri * 256 + tid;
        float b = bih[r] + bhh[r];
        #pragma unroll
        for (int tt = 0; tt < 16; ++tt)
            gates[(size_t)(t0 + tt) * 1024 + r] = acc[ri][tt] + b;
    }
}

// ---------------------------------------------------------------------------
// Kernel 2: BiLSTM recurrence — R5's low-traffic sync (1 slot/poller -> LDS
// -> barrier) + dual-direction interleave per block. 8 blocks; block b owns
// hidden j = b*32..b*32+31 for BOTH directions. 256 threads: thread
// (jl = tid>>3, s = tid&7) computes 4 gates of hidden j over k-slice
// s*32..s*32+31, for f AND b (128+128 weight floats, asm-pinned).
// Per step: poll-f -> barrier -> dot-f -> publish-f -> poll-b -> barrier ->
// dot-b -> publish-b. Each direction's store->visible RTT drains during the
// other direction's compute phase. R6 lesson: poll fan-out must be 1
// slot/thread, polled into LDS — never 16 slots/thread into registers
// (92 MB FETCH poll storm, 8x regression).
// ---------------------------------------------------------------------------
__global__ __launch_bounds__(256, 1) void lstm_kernel(
    const float* __restrict__ Whh_f, const float* __restrict__ Whh_b,
    const float* __restrict__ gates_f, const float* __restrict__ gates_b,
    const float* __restrict__ h0, const float* __restrict__ c0,
    float* __restrict__ h_out, u64* __restrict__ msg)
{
    const int b   = blockIdx.x;       // 0..7
    const int tid = threadIdx.x;
    const int s   = tid & 7;          // k-slice 0..7 (32 k each)
    const int jl  = tid >> 3;         // 0..31
    const int j   = b * 32 + jl;      // hidden index 0..255

    // wf/wb[g*32 + i*4 + c] = Whh_d[(g*256+j)*256 + s*32 + ((i+s)&7)*4 + c]
    // (rotation (i+s)&7 -> conflict-free LDS banks across the 8 s-groups)
    float wf[128], wb[128];
    #pragma unroll
    for (int g = 0; g < 4; ++g) {
        const float4* rf = (const float4*)(Whh_f + (size_t)(g * 256 + j) * 256 + s * 32);
        const float4* rb = (const float4*)(Whh_b + (size_t)(g * 256 + j) * 256 + s * 32);
        #pragma unroll
        for (int i = 0; i < 8; ++i) {
            int idx = (i + s) & 7;
            float4 vf = rf[idx], vb = rb[idx];
            wf[g*32 + i*4 + 0] = vf.x; wf[g*32 + i*4 + 1] = vf.y;
            wf[g*32 + i*4 + 2] = vf.z; wf[g*32 + i*4 + 3] = vf.w;
            wb[g*32 + i*4 + 0] = vb.x; wb[g*32 + i*4 + 1] = vb.y;
            wb[g*32 + i*4 + 2] = vb.z; wb[g*32 + i*4 + 3] = vb.w;
        }
    }
    #pragma unroll
    for (int k = 0; k < 128; ++k) {
        asm volatile("" : "+v"(wf[k]));
        asm volatile("" : "+v"(wb[k]));
    }

    __shared__ __align__(16) float h_f[2][256];
    __shared__ __align__(16) float h_b[2][256];

    // init: every block stores all 256 tag-1 slots for both dirs (identical
    // values -> benign), and seeds its LDS parity-0 buffers.
    {
        float hf0 = h0[tid], hb0 = h0[HH + tid];
        h_f[0][tid] = hf0;
        h_b[0][tid] = hb0;
        __hip_atomic_store(&msg[(0 * 2 + 0) * 256 + tid],
                           ((u64)1u << 32) | (u64)__float_as_uint(hf0),
                           __ATOMIC_RELAXED, __HIP_MEMORY_SCOPE_AGENT);
        __hip_atomic_store(&msg[(0 * 2 + 1) * 256 + tid],
                           ((u64)1u << 32) | (u64)__float_as_uint(hb0),
                           __ATOMIC_RELAXED, __HIP_MEMORY_SCOPE_AGENT);
    }
    float cf = 0.f, cb = 0.f;
    if (s == 0) { cf = c0[j]; cb = c0[HH + j]; }

    const bool remote = (tid >> 5) != b;   // slot tid not owned by this block

    for (int t = 0; t < T_LEN; ++t) {
        const int tb = T_LEN - 1 - t;
        const unsigned want = (unsigned)(t + 1);
        const u64 newtag = ((u64)(unsigned)(t + 2)) << 32;
        const int par = t & 1, nxt = (t + 1) & 1;

        // finalists prefetch both directions' gate inputs (overlaps poll)
        float gf0 = 0.f, gf1 = 0.f, gf2 = 0.f, gf3 = 0.f;
        float gb0 = 0.f, gb1 = 0.f, gb2 = 0.f, gb3 = 0.f;
        if (s == 0) {
            const float* gpf = gates_f + (size_t)t  * 1024 + j;
            const float* gpb = gates_b + (size_t)tb * 1024 + j;
            gf0 = gpf[0]; gf1 = gpf[256]; gf2 = gpf[512]; gf3 = gpf[768];
            gb0 = gpb[0]; gb1 = gpb[256]; gb2 = gpb[512]; gb3 = gpb[768];
        }

        // ================= phase F =================
        if (remote) {
            u64* sp = &msg[(par * 2 + 0) * 256 + tid];
            u64 m;
            do {
                m = __hip_atomic_load(sp, __ATOMIC_RELAXED, __HIP_MEMORY_SCOPE_AGENT);
            } while ((unsigned)(m >> 32) != want);
            h_f[par][tid] = __uint_as_float((unsigned)m);
        }
        __syncthreads();

        {
            float p0 = 0.f, p1 = 0.f, p2 = 0.f, p3 = 0.f;
            const float4* hp = (const float4*)(&h_f[par][s * 32]);
            #pragma unroll
            for (int i = 0; i < 8; ++i) {
                float4 h4 = hp[(i + s) & 7];
                p0 += wf[i*4+0]*h4.x + wf[i*4+1]*h4.y + wf[i*4+2]*h4.z + wf[i*4+3]*h4.w;
                p1 += wf[32+i*4+0]*h4.x + wf[32+i*4+1]*h4.y + wf[32+i*4+2]*h4.z + wf[32+i*4+3]*h4.w;
                p2 += wf[64+i*4+0]*h4.x + wf[64+i*4+1]*h4.y + wf[64+i*4+2]*h4.z + wf[64+i*4+3]*h4.w;
                p3 += wf[96+i*4+0]*h4.x + wf[96+i*4+1]*h4.y + wf[96+i*4+2]*h4.z + wf[96+i*4+3]*h4.w;
            }
            #pragma unroll
            for (int mk = 1; mk <= 4; mk <<= 1) {
                p0 += __shfl_xor(p0, mk); p1 += __shfl_xor(p1, mk);
                p2 += __shfl_xor(p2, mk); p3 += __shfl_xor(p3, mk);
            }
            if (s == 0) {
                float iv = sigmoidf_(gf0 + p0);
                float fv = sigmoidf_(gf1 + p1);
                float gv = tanh_fast(gf2 + p2);
                float ov = sigmoidf_(gf3 + p3);
                cf = fv * cf + iv * gv;
                float h = ov * tanh_fast(cf);
                __hip_atomic_store(&msg[(nxt * 2 + 0) * 256 + j],
                                   newtag | (u64)__float_as_uint(h),
                                   __ATOMIC_RELAXED, __HIP_MEMORY_SCOPE_AGENT);
                h_f[nxt][j] = h;
                h_out[(size_t)t * 512 + j] = h;
            }
        }

        // ================= phase B =================
        // (f's store drains to the coherence point while we do all of this)
        if (remote) {
            u64* sp = &msg[(par * 2 + 1) * 256 + tid];
            u64 m;
            do {
                m = __hip_atomic_load(sp, __ATOMIC_RELAXED, __HIP_MEMORY_SCOPE_AGENT);
            } while ((unsigned)(m >> 32) != want);
            h_b[par][tid] = __uint_as_float((unsigned)m);
        }
        __syncthreads();

        {
            float p0 = 0.f, p1 = 0.f, p2 = 0.f, p3 = 0.f;
            const float4* hp = (const float4*)(&h_b[par][s * 32]);
            #pragma unroll
            for (int i = 0; i < 8; ++i) {
                float4 h4 = hp[(i + s) & 7];
                p0 += wb[i*4+0]*h4.x + wb[i*4+1]*h4.y + wb[i*4+2]*h4.z + wb[i*4+3]*h4.w;
                p1 += wb[32+i*4+0]*h4.x + wb[32+i*4+1]*h4.y + wb[32+i*4+2]*h4.z + wb[32+i*4+3]*h4.w;
                p2 += wb[64+i*4+0]*h4.x + wb[64+i*4+1]*h4.y + wb[64+i*4+2]*h4.z + wb[64+i*4+3]*h4.w;
                p3 += wb[96+i*4+0]*h4.x + wb[96+i*4+1]*h4.y + wb[96+i*4+2]*h4.z + wb[96+i*4+3]*h4.w;
            }
            #pragma unroll
            for (int mk = 1; mk <= 4; mk <<= 1) {
                p0 += __shfl_xor(p0, mk); p1 += __shfl_xor(p1, mk);
                p2 += __shfl_xor(p2, mk); p3 += __shfl_xor(p3, mk);
            }
            if (s == 0) {
                float iv = sigmoidf_(gb0 + p0);
                float fv = sigmoidf_(gb1 + p1);
                float gv = tanh_fast(gb2 + p2);
                float ov = sigmoidf_(gb3 + p3);
                cb = fv * cb + iv * gv;
                float h = ov * tanh_fast(cb);
                __hip_atomic_store(&msg[(nxt * 2 + 1) * 256 + j],
                                   newtag | (u64)__float_as_uint(h),
                                   __ATOMIC_RELAXED, __HIP_MEMORY_SCOPE_AGENT);
                h_b[nxt][j] = h;
                h_out[(size_t)tb * 512 + HH + j] = h;
            }
        }
        // ABA per direction: publishing tag t+2 on slots that held tag t is
        // safe because our same-direction poll saw tag t+1 on every remote
        // block, and each block's publish of t+1 sits behind its poll of
        // tag t + a barrier -> all consumers of tag t are done.
    }
}

// ---------------------------------------------------------------------------
// Kernel 3: feats[t][k] = dot(h_out[t,:], W_out[k,:]) + b_out[k]
// ---------------------------------------------------------------------------
__global__ __launch_bounds__(64) void feats_kernel(
    const float* __restrict__ h_out, const float* __restrict__ W_out,
    const float* __restrict__ b_out, float* __restrict__ feats)
{
    const int t = blockIdx.x;
    const int lane = threadIdx.x;
    const int k = lane >> 1, half = lane & 1;
    const float4* hv = (const float4*)(h_out + (size_t)t * 512 + half * 256);
    const float4* wv = (const float4*)(W_out + (size_t)k * 512 + half * 256);
    float p = 0.f;
    #pragma unroll 16
    for (int i = 0; i < 64; ++i) {
        float4 a = hv[i], b = wv[i];
        p += a.x*b.x + a.y*b.y + a.z*b.z + a.w*b.w;
    }
    p += __shfl_xor(p, 1);
    if (half == 0) feats[t * 32 + k] = p + b_out[k];
}

// ---------------------------------------------------------------------------
// Kernel 4: Viterbi — R4 version (shfl alpha broadcast), reverted from R5's
// LDS-alpha variant to de-risk the unexplained residual growth.
// ---------------------------------------------------------------------------
#define VT_CHUNK 128
__global__ __launch_bounds__(64) void viterbi_kernel(
    const float* __restrict__ feats, const float* __restrict__ trans,
    float* __restrict__ out)
{
    extern __shared__ unsigned char dynls[];
    unsigned char* ixs = dynls;                       // (T-1)*32 = 131040 B
    float* fchunk = (float*)(dynls + 131072);         // VT_CHUNK*32 floats
    __shared__ float fin[32];

    const int lane = threadIdx.x;
    const int j = lane >> 1, ih = lane & 1;

    float ttr[16];
    #pragma unroll
    for (int q = 0; q < 16; ++q) ttr[q] = trans[(ih * 16 + q) * 32 + j];

    float alpha = 0.f;

    for (int cs = 0; cs < T_LEN; cs += VT_CHUNK) {
        const float4* src = (const float4*)(feats + (size_t)cs * 32);
        float4* dst = (float4*)fchunk;
        #pragma unroll
        for (int i = 0; i < 16; ++i) dst[lane + 64 * i] = src[lane + 64 * i];
        __syncthreads();

        int tbeg = cs;
        if (cs == 0) { alpha = fchunk[j]; tbeg = 1; }

        for (int t = tbeg; t < cs + VT_CHUNK; ++t) {
            float obs = fchunk[(t - cs) * 32 + j];
            float v[16]; int ix[16];
            #pragma unroll
            for (int q = 0; q < 16; ++q) {
                int i = ih * 16 + q;
                v[q] = (__shfl(alpha, 2 * i) + ttr[q]) + obs;
                ix[q] = i;
            }
            #pragma unroll
            for (int st = 8; st >= 1; st >>= 1)
                #pragma unroll
                for (int q = 0; q < 8; ++q)
                    if (q < st && v[q + st] > v[q]) { v[q] = v[q + st]; ix[q] = ix[q + st]; }
            float best = v[0]; int barg = ix[0];

            float ob = __shfl_xor(best, 1); int oa = __shfl_xor(barg, 1);
            float m0 = ih ? ob : best; int a0 = ih ? oa : barg;
            float m1 = ih ? best : ob; int a1 = ih ? barg : oa;
            float m = m0; int a = a0;
            if (m1 > m0) { m = m1; a = a1; }
            if (ih == 0) ixs[(t - 1) * 32 + j] = (unsigned char)a;
            alpha = m;
        }
        __syncthreads();
    }

    if (ih == 0) fin[j] = alpha;
    __syncthreads();

    if (lane == 0) {
        float sc = fin[0]; int cur = 0;
        for (int q = 1; q < 32; ++q)
            if (fin[q] > sc) { sc = fin[q]; cur = q; }
        out[T_LEN] = sc;
        out[T_LEN - 1] = (float)cur;
        for (int t = T_LEN - 2; t >= 0; --t) {
            cur = ixs[t * 32 + cur];
            out[t] = (float)cur;
        }
    }
}

// ---------------------------------------------------------------------------
extern "C" void kernel_launch(void* const* d_in, const int* in_sizes, int n_in,
                              void* d_out, int out_size, void* d_ws, size_t ws_size,
                              hipStream_t stream) {
    const int*   sent  = (const int*)d_in[0];
    const float* embed = (const float*)d_in[1];
    const float* Wih_f = (const float*)d_in[2];
    const float* Whh_f = (const float*)d_in[3];
    const float* bih_f = (const float*)d_in[4];
    const float* bhh_f = (const float*)d_in[5];
    const float* Wih_b = (const float*)d_in[6];
    const float* Whh_b = (const float*)d_in[7];
    const float* bih_b = (const float*)d_in[8];
    const float* bhh_b = (const float*)d_in[9];
    const float* h0    = (const float*)d_in[10];
    const float* c0    = (const float*)d_in[11];
    const float* W_out = (const float*)d_in[12];
    const float* b_out = (const float*)d_in[13];
    const float* trans = (const float*)d_in[14];
    float* out = (float*)d_out;

    float* gates_f = (float*)d_ws;                              // T*1024
    float* gates_b = gates_f + (size_t)T_LEN * 1024;            // T*1024
    float* h_out   = gates_b + (size_t)T_LEN * 1024;            // T*512
    float* feats   = h_out   + (size_t)T_LEN * 512;             // T*32
    u64*   msg     = (u64*)(feats + (size_t)T_LEN * 32);        // 2*2*256

    dim3 gproj(T_LEN / 16, 2);
    proj_kernel<<<gproj, 256, 0, stream>>>(sent, embed,
        Wih_f, bih_f, bhh_f, Wih_b, bih_b, bhh_b, gates_f, gates_b);

    lstm_kernel<<<8, 256, 0, stream>>>(Whh_f, Whh_b, gates_f, gates_b,
                                       h0, c0, h_out, msg);

    feats_kernel<<<T_LEN, 64, 0, stream>>>(h_out, W_out, b_out, feats);

    hipFuncSetAttribute((const void*)viterbi_kernel,
                        hipFuncAttributeMaxDynamicSharedMemorySize, 147456);
    viterbi_kernel<<<1, 64, 147456, stream>>>(feats, trans, out);
}